// Round 5
// baseline (570.052 us; speedup 1.0000x reference)
//
#include <hip/hip_runtime.h>
#include <hip/hip_bf16.h>

typedef __hip_bfloat16 bf16;
typedef __attribute__((ext_vector_type(8))) short short8;   // 8 bf16 = 4 VGPRs (MFMA A/B frag)
typedef __attribute__((ext_vector_type(4))) float f32x4;    // MFMA C/D frag

// exact bf16<->f32 conversion helpers (bf16 = top 16 bits of f32, RNE round)
__device__ __forceinline__ float us2f(unsigned short u) {
  union { unsigned int ui; float f; } cv; cv.ui = ((unsigned int)u) << 16; return cv.f;
}
__device__ __forceinline__ unsigned short f2us(float f) {
  union { float f; unsigned int u; } cv; cv.f = f;
  unsigned int u = cv.u;
  return (unsigned short)((u + 0x7fffu + ((u >> 16) & 1u)) >> 16);
}
// unpack low/high bf16 of a packed dword (low ushort = even feature)
__device__ __forceinline__ float lo2f(unsigned int u) {
  union { unsigned int ui; float f; } cv; cv.ui = u << 16; return cv.f;
}
__device__ __forceinline__ float hi2f(unsigned int u) {
  union { unsigned int ui; float f; } cv; cv.ui = u & 0xffff0000u; return cv.f;
}

#define WEXP 0.36787944117144233f  // exp(-1)

// MFMA dense+ReLU: fout[n][64] = bf16(relu(in[n][KDIM] @ W[KDIM][64] + b)).
// (Used for layer 0 only; layer 1 is fused into the accumulate kernel.)
// Operand-swapped MFMA: D = Wfrag * xfrag -> lane owns 4 consecutive out cols.
// W staged in LDS in exact frag order (16B/lane, lane-consecutive).
// Precision: x split hi/lo (two MFMAs) recovers ~fp32 x; only W bf16-rounded.
template<int KDIM>
__global__ __launch_bounds__(256) void dense_mfma_kernel(
    const float* __restrict__ in, int in_stride,
    const float* __restrict__ W, const float* __restrict__ b,
    bf16* __restrict__ fout, float* __restrict__ xcopy, int n)
{
  constexpr int NKS = KDIM / 32;
  constexpr int NFRAG = NKS * 4 * 64;
  __shared__ unsigned short WTf[NFRAG * 8];

  const int tx = threadIdx.x;
#pragma unroll
  for (int fch = 0; fch < NFRAG / 256; ++fch) {
    const int fi = fch * 256 + tx;
    const int ln = fi & 63;
    const int ct = (fi >> 6) & 3;
    const int ks = fi >> 8;
    const int c  = ct * 16 + (ln & 15);
    const int kb = ks * 32 + (ln >> 4) * 8;
    short8 wf;
#pragma unroll
    for (int j = 0; j < 8; ++j)
      wf[j] = (short)f2us(W[(size_t)(kb + j) * 64 + c]);
    *(short8*)&WTf[(size_t)fi * 8] = wf;
  }
  __syncthreads();

  const int wv = tx >> 6;
  const int lane = tx & 63;
  const int mrow = lane & 15;
  const int kgrp = lane >> 4;
  const int row = blockIdx.x * 64 + wv * 16 + mrow;

  f32x4 acc[4] = {};

#pragma unroll
  for (int ks = 0; ks < NKS; ++ks) {
    const int k0 = ks * 32 + kgrp * 8;
    float4 a0 = make_float4(0.f, 0.f, 0.f, 0.f);
    float4 a1 = make_float4(0.f, 0.f, 0.f, 0.f);
    if (row < n) {
      a0 = *(const float4*)(in + (size_t)row * in_stride + k0);
      a1 = *(const float4*)(in + (size_t)row * in_stride + k0 + 4);
    }
    if (xcopy != nullptr && row < n) {
      *(float4*)(xcopy + (size_t)row * 320 + k0) = a0;
      *(float4*)(xcopy + (size_t)row * 320 + k0 + 4) = a1;
    }
    short8 xhi, xlo;
    const float av[8] = {a0.x, a0.y, a0.z, a0.w, a1.x, a1.y, a1.z, a1.w};
#pragma unroll
    for (int j = 0; j < 8; ++j) {
      const unsigned short h = f2us(av[j]);
      xhi[j] = (short)h;
      xlo[j] = (short)f2us(av[j] - us2f(h));
    }
#pragma unroll
    for (int ct = 0; ct < 4; ++ct) {
      const short8 wfr = *(const short8*)&WTf[(size_t)((ks * 4 + ct) * 64 + lane) * 8];
      acc[ct] = __builtin_amdgcn_mfma_f32_16x16x32_bf16(wfr, xhi, acc[ct], 0, 0, 0);
      acc[ct] = __builtin_amdgcn_mfma_f32_16x16x32_bf16(wfr, xlo, acc[ct], 0, 0, 0);
    }
  }

  if (row < n) {
    unsigned short* fr = (unsigned short*)fout + (size_t)row * 64;
#pragma unroll
    for (int ct = 0; ct < 4; ++ct) {
      const int c0 = ct * 16 + kgrp * 4;
      const float4 bb = *(const float4*)&b[c0];
      ushort4 o;
      o.x = f2us(fmaxf(acc[ct][0] + bb.x, 0.f));
      o.y = f2us(fmaxf(acc[ct][1] + bb.y, 0.f));
      o.z = f2us(fmaxf(acc[ct][2] + bb.z, 0.f));
      o.w = f2us(fmaxf(acc[ct][3] + bb.w, 0.f));
      *(ushort4*)&fr[c0] = o;
    }
  }
}

// ---------------------------------------------------------------------------
// Fused accumulate(layer0) + dense(layer1):
//   phase 1: for 64 points/block, gather f0 neighbors, compute
//            out0 = {WEXP*mean - self, WEXP*max - self}; write to global out
//            (cols 0..127) AND stage in LDS SX (fp32).
//   phase 2: f1 = bf16(relu(SX @ W1 + b1)) via operand-swapped MFMA.
// Eliminates dense1's 102.4 MB re-read of out0 from HBM.
// f1 must be a DIFFERENT buffer from f0 (other blocks still gather f0).
__global__ __launch_bounds__(256) void accum_dense_fused_kernel(
    const bf16* __restrict__ f0,    // [n][64] bf16
    const int* __restrict__ idx,    // [n][32] int32
    const float* __restrict__ W,    // W1 [128][64]
    const float* __restrict__ b,    // b1 [64]
    float* __restrict__ out,        // fp32, cols 0..127 base, row stride 320
    bf16* __restrict__ f1,          // [n][64] bf16 (distinct from f0!)
    int n)
{
  __shared__ unsigned short WTf[1024 * 8];  // 16 KB: W1 frags, KDIM=128
  __shared__ float SX[64][132];             // 33 KB: out0 staging (132: bank-spread)

  const int tx = threadIdx.x;
  const int p0 = blockIdx.x * 64;

  // stage W1 frags: fi = (ks*4+ct)*64+lane, KDIM=128 -> NKS=4, NFRAG=1024
#pragma unroll
  for (int fch = 0; fch < 4; ++fch) {
    const int fi = fch * 256 + tx;
    const int ln = fi & 63;
    const int ct = (fi >> 6) & 3;
    const int ks = fi >> 8;
    const int c  = ct * 16 + (ln & 15);
    const int kb = ks * 32 + (ln >> 4) * 8;
    short8 wf;
#pragma unroll
    for (int j = 0; j < 8; ++j)
      wf[j] = (short)f2us(W[(size_t)(kb + j) * 64 + c]);
    *(short8*)&WTf[(size_t)fi * 8] = wf;
  }

  const int wv = tx >> 6;          // wave 0..3; wave handles points wv*16..wv*16+15
  const int lane = tx & 63;
  const int oct = lane >> 3;       // 8 lanes/oct; oct owns 4 neighbor slots
  const unsigned Lo16 = ((unsigned)(lane & 7)) << 4;  // 16B feature slot in a row
  const char* fb = (const char*)f0;
  const float cmean = WEXP / 32.0f;

  // ---- phase 1: gather + reduce, 16 points per wave, 2-stage pipelined ----
  // idx rows for this wave's 16 points: 2 KB contiguous; 2 uint4 vector loads.
  // uint4 #j of the 2KB covers point j>>3; for point pt, oct o, neighbor slot
  // t: value = component t of the uint4 held by lane (pt&7)*8+o.
  const uint4* idxv = (const uint4*)(idx + (size_t)(p0 + wv * 16) * 32);
  uint4 q0 = make_uint4(0u, 0u, 0u, 0u), q1 = make_uint4(0u, 0u, 0u, 0u);
  if (p0 + wv * 16 + (lane >> 3) < n)     q0 = idxv[lane];
  if (p0 + wv * 16 + 8 + (lane >> 3) < n) q1 = idxv[64 + lane];

#define ISSUE(pt, SD, D0, D1, D2, D3)                                        \
  {                                                                          \
    const uint4 q = ((pt) < 8) ? q0 : q1;                                    \
    const int srcl = (((pt) & 7) << 3) + oct;                                \
    const int n0 = __shfl((int)q.x, srcl);                                   \
    const int n1 = __shfl((int)q.y, srcl);                                   \
    const int n2 = __shfl((int)q.z, srcl);                                   \
    const int n3 = __shfl((int)q.w, srcl);                                   \
    const int ii = p0 + wv * 16 + (pt);                                      \
    if (ii < n) {                                                            \
      SD = *(const uint4*)(fb + (((unsigned)ii) << 7) + Lo16);               \
      D0 = *(const uint4*)(fb + (((unsigned)n0) << 7) + Lo16);               \
      D1 = *(const uint4*)(fb + (((unsigned)n1) << 7) + Lo16);               \
      D2 = *(const uint4*)(fb + (((unsigned)n2) << 7) + Lo16);               \
      D3 = *(const uint4*)(fb + (((unsigned)n3) << 7) + Lo16);               \
    }                                                                        \
  }

#define UNP(D)                                                               \
  { float v;                                                                 \
    v = lo2f(D.x); s0 += v; m0 = fmaxf(m0, v);                               \
    v = hi2f(D.x); s1 += v; m1 = fmaxf(m1, v);                               \
    v = lo2f(D.y); s2 += v; m2 = fmaxf(m2, v);                               \
    v = hi2f(D.y); s3 += v; m3 = fmaxf(m3, v);                               \
    v = lo2f(D.z); s4 += v; m4 = fmaxf(m4, v);                               \
    v = hi2f(D.z); s5 += v; m5 = fmaxf(m5, v);                               \
    v = lo2f(D.w); s6 += v; m6 = fmaxf(m6, v);                               \
    v = hi2f(D.w); s7 += v; m7 = fmaxf(m7, v); }

#define BFLY(off)                                                            \
  { s0 += __shfl_xor(s0, off); m0 = fmaxf(m0, __shfl_xor(m0, off));          \
    s1 += __shfl_xor(s1, off); m1 = fmaxf(m1, __shfl_xor(m1, off));          \
    s2 += __shfl_xor(s2, off); m2 = fmaxf(m2, __shfl_xor(m2, off));          \
    s3 += __shfl_xor(s3, off); m3 = fmaxf(m3, __shfl_xor(m3, off));          \
    s4 += __shfl_xor(s4, off); m4 = fmaxf(m4, __shfl_xor(m4, off));          \
    s5 += __shfl_xor(s5, off); m5 = fmaxf(m5, __shfl_xor(m5, off));          \
    s6 += __shfl_xor(s6, off); m6 = fmaxf(m6, __shfl_xor(m6, off));          \
    s7 += __shfl_xor(s7, off); m7 = fmaxf(m7, __shfl_xor(m7, off)); }

#define REDUCE(pt, SD, D0, D1, D2, D3)                                       \
  {                                                                          \
    float s0 = 0.f, s1 = 0.f, s2 = 0.f, s3 = 0.f,                            \
          s4 = 0.f, s5 = 0.f, s6 = 0.f, s7 = 0.f;                            \
    float m0 = -3.4e38f, m1 = -3.4e38f, m2 = -3.4e38f, m3 = -3.4e38f,        \
          m4 = -3.4e38f, m5 = -3.4e38f, m6 = -3.4e38f, m7 = -3.4e38f;        \
    UNP(D0) UNP(D1) UNP(D2) UNP(D3)                                          \
    BFLY(8) BFLY(16) BFLY(32)                                                \
    const int ii = p0 + wv * 16 + (pt);                                      \
    if (ii < n) {                                                            \
      float4 a, bq;                                                          \
      if (oct == 0) {                                                        \
        a.x  = s0 * cmean - lo2f(SD.x); a.y  = s1 * cmean - hi2f(SD.x);      \
        a.z  = s2 * cmean - lo2f(SD.y); a.w  = s3 * cmean - hi2f(SD.y);      \
        bq.x = s4 * cmean - lo2f(SD.z); bq.y = s5 * cmean - hi2f(SD.z);      \
        bq.z = s6 * cmean - lo2f(SD.w); bq.w = s7 * cmean - hi2f(SD.w);      \
        float* orow = out + (size_t)ii * 320 + 8 * (lane & 7);               \
        *(float4*)orow = a; *(float4*)(orow + 4) = bq;                       \
        float* sx = &SX[wv * 16 + (pt)][8 * (lane & 7)];                     \
        *(float4*)sx = a; *(float4*)(sx + 4) = bq;                           \
      } else if (oct == 1) {                                                 \
        a.x  = m0 * WEXP - lo2f(SD.x); a.y  = m1 * WEXP - hi2f(SD.x);        \
        a.z  = m2 * WEXP - lo2f(SD.y); a.w  = m3 * WEXP - hi2f(SD.y);        \
        bq.x = m4 * WEXP - lo2f(SD.z); bq.y = m5 * WEXP - hi2f(SD.z);        \
        bq.z = m6 * WEXP - lo2f(SD.w); bq.w = m7 * WEXP - hi2f(SD.w);        \
        float* orow = out + (size_t)ii * 320 + 64 + 8 * (lane & 7);          \
        *(float4*)orow = a; *(float4*)(orow + 4) = bq;                       \
        float* sx = &SX[wv * 16 + (pt)][64 + 8 * (lane & 7)];                \
        *(float4*)sx = a; *(float4*)(sx + 4) = bq;                           \
      }                                                                      \
    }                                                                        \
  }

  {
    uint4 sA, a0, a1, a2, a3, sB, b0q, b1q, b2q, b3q;
    ISSUE(0, sA, a0, a1, a2, a3)
    ISSUE(1, sB, b0q, b1q, b2q, b3q)
    REDUCE(0, sA, a0, a1, a2, a3)
    ISSUE(2, sA, a0, a1, a2, a3)
    REDUCE(1, sB, b0q, b1q, b2q, b3q)
    ISSUE(3, sB, b0q, b1q, b2q, b3q)
    REDUCE(2, sA, a0, a1, a2, a3)
    ISSUE(4, sA, a0, a1, a2, a3)
    REDUCE(3, sB, b0q, b1q, b2q, b3q)
    ISSUE(5, sB, b0q, b1q, b2q, b3q)
    REDUCE(4, sA, a0, a1, a2, a3)
    ISSUE(6, sA, a0, a1, a2, a3)
    REDUCE(5, sB, b0q, b1q, b2q, b3q)
    ISSUE(7, sB, b0q, b1q, b2q, b3q)
    REDUCE(6, sA, a0, a1, a2, a3)
    ISSUE(8, sA, a0, a1, a2, a3)
    REDUCE(7, sB, b0q, b1q, b2q, b3q)
    ISSUE(9, sB, b0q, b1q, b2q, b3q)
    REDUCE(8, sA, a0, a1, a2, a3)
    ISSUE(10, sA, a0, a1, a2, a3)
    REDUCE(9, sB, b0q, b1q, b2q, b3q)
    ISSUE(11, sB, b0q, b1q, b2q, b3q)
    REDUCE(10, sA, a0, a1, a2, a3)
    ISSUE(12, sA, a0, a1, a2, a3)
    REDUCE(11, sB, b0q, b1q, b2q, b3q)
    ISSUE(13, sB, b0q, b1q, b2q, b3q)
    REDUCE(12, sA, a0, a1, a2, a3)
    ISSUE(14, sA, a0, a1, a2, a3)
    REDUCE(13, sB, b0q, b1q, b2q, b3q)
    ISSUE(15, sB, b0q, b1q, b2q, b3q)
    REDUCE(14, sA, a0, a1, a2, a3)
    REDUCE(15, sB, b0q, b1q, b2q, b3q)
  }
#undef ISSUE
#undef UNP
#undef BFLY
#undef REDUCE

  __syncthreads();

  // ---- phase 2: f1 = bf16(relu(SX @ W1 + b1)), SX in LDS ----
  const int mrow = lane & 15;
  const int kgrp = lane >> 4;
  const int row = p0 + wv * 16 + mrow;

  f32x4 acc[4] = {};
#pragma unroll
  for (int ks = 0; ks < 4; ++ks) {
    const int k0 = ks * 32 + kgrp * 8;
    const float4 a0 = *(const float4*)&SX[wv * 16 + mrow][k0];
    const float4 a1 = *(const float4*)&SX[wv * 16 + mrow][k0 + 4];
    short8 xhi, xlo;
    const float av[8] = {a0.x, a0.y, a0.z, a0.w, a1.x, a1.y, a1.z, a1.w};
#pragma unroll
    for (int j = 0; j < 8; ++j) {
      const unsigned short h = f2us(av[j]);
      xhi[j] = (short)h;
      xlo[j] = (short)f2us(av[j] - us2f(h));
    }
#pragma unroll
    for (int ct = 0; ct < 4; ++ct) {
      const short8 wfr = *(const short8*)&WTf[(size_t)((ks * 4 + ct) * 64 + lane) * 8];
      acc[ct] = __builtin_amdgcn_mfma_f32_16x16x32_bf16(wfr, xhi, acc[ct], 0, 0, 0);
      acc[ct] = __builtin_amdgcn_mfma_f32_16x16x32_bf16(wfr, xlo, acc[ct], 0, 0, 0);
    }
  }

  if (row < n) {
    unsigned short* fr = (unsigned short*)f1 + (size_t)row * 64;
#pragma unroll
    for (int ct = 0; ct < 4; ++ct) {
      const int c0 = ct * 16 + kgrp * 4;
      const float4 bb = *(const float4*)&b[c0];
      ushort4 o;
      o.x = f2us(fmaxf(acc[ct][0] + bb.x, 0.f));
      o.y = f2us(fmaxf(acc[ct][1] + bb.y, 0.f));
      o.z = f2us(fmaxf(acc[ct][2] + bb.z, 0.f));
      o.w = f2us(fmaxf(acc[ct][3] + bb.w, 0.f));
      *(ushort4*)&fr[c0] = o;
    }
  }
}

// KNN accumulate (layer 1 output). One wave per point; 4 waves/block.
// Each oct (8 lanes) owns 4 neighbors; lane L=lane&7 holds features 8L..8L+7;
// all 5 gathers (self + 4 neighbor chunks) issued before any reduction.
__global__ __launch_bounds__(256) void accum_kernel(
    const bf16* __restrict__ f,     // [n][64] bf16
    const int* __restrict__ idx,    // [n][32] int32
    float* __restrict__ out,        // fp32, row stride 320
    int n)
{
  const int wid = threadIdx.x >> 6;
  const int lane = threadIdx.x & 63;
  const int i = blockIdx.x * 4 + wid;
  if (i >= n) return;

  int iv = 0;
  if (lane < 32) iv = idx[(size_t)i * 32 + lane];

  const int L = lane & 7;
  const int srcbase = (lane >> 3) << 2;
  const char* fb = (const char*)f;

  const uint4 sd = *(const uint4*)(fb + (((unsigned)i) << 7) + ((unsigned)L << 4));

  int nk[4];
#pragma unroll
  for (int t = 0; t < 4; ++t) nk[t] = __shfl(iv, srcbase + t);

  uint4 d[4];
#pragma unroll
  for (int t = 0; t < 4; ++t)
    d[t] = *(const uint4*)(fb + (((unsigned)nk[t]) << 7) + ((unsigned)L << 4));

  float s[8], m[8];
#pragma unroll
  for (int j = 0; j < 8; ++j) { s[j] = 0.f; m[j] = -3.4e38f; }
#pragma unroll
  for (int t = 0; t < 4; ++t) {
    float v;
    v = lo2f(d[t].x); s[0] += v; m[0] = fmaxf(m[0], v);
    v = hi2f(d[t].x); s[1] += v; m[1] = fmaxf(m[1], v);
    v = lo2f(d[t].y); s[2] += v; m[2] = fmaxf(m[2], v);
    v = hi2f(d[t].y); s[3] += v; m[3] = fmaxf(m[3], v);
    v = lo2f(d[t].z); s[4] += v; m[4] = fmaxf(m[4], v);
    v = hi2f(d[t].z); s[5] += v; m[5] = fmaxf(m[5], v);
    v = lo2f(d[t].w); s[6] += v; m[6] = fmaxf(m[6], v);
    v = hi2f(d[t].w); s[7] += v; m[7] = fmaxf(m[7], v);
  }

#pragma unroll
  for (int off = 8; off <= 32; off <<= 1) {
#pragma unroll
    for (int j = 0; j < 8; ++j) {
      s[j] += __shfl_xor(s[j], off);
      m[j] = fmaxf(m[j], __shfl_xor(m[j], off));
    }
  }

  float self[8];
  self[0] = lo2f(sd.x); self[1] = hi2f(sd.x);
  self[2] = lo2f(sd.y); self[3] = hi2f(sd.y);
  self[4] = lo2f(sd.z); self[5] = hi2f(sd.z);
  self[6] = lo2f(sd.w); self[7] = hi2f(sd.w);

  const float cmean = WEXP / 32.0f;
  const int o = lane >> 3;
  float* orow = out + (size_t)i * 320;
  if (o == 0) {
    float4 a, bq;
    a.x = s[0] * cmean - self[0]; a.y = s[1] * cmean - self[1];
    a.z = s[2] * cmean - self[2]; a.w = s[3] * cmean - self[3];
    bq.x = s[4] * cmean - self[4]; bq.y = s[5] * cmean - self[5];
    bq.z = s[6] * cmean - self[6]; bq.w = s[7] * cmean - self[7];
    *(float4*)(orow + 8 * L) = a;
    *(float4*)(orow + 8 * L + 4) = bq;
  } else if (o == 1) {
    float4 a, bq;
    a.x = m[0] * WEXP - self[0]; a.y = m[1] * WEXP - self[1];
    a.z = m[2] * WEXP - self[2]; a.w = m[3] * WEXP - self[3];
    bq.x = m[4] * WEXP - self[4]; bq.y = m[5] * WEXP - self[5];
    bq.z = m[6] * WEXP - self[6]; bq.w = m[7] * WEXP - self[7];
    *(float4*)(orow + 64 + 8 * L) = a;
    *(float4*)(orow + 64 + 8 * L + 4) = bq;
  }
}

extern "C" void kernel_launch(void* const* d_in, const int* in_sizes, int n_in,
                              void* d_out, int out_size, void* d_ws, size_t ws_size,
                              hipStream_t stream) {
  const float* x  = (const float*)d_in[0];
  const int* idx  = (const int*)d_in[1];   // int64 in reference, narrowed to int32 on device
  const float* W0 = (const float*)d_in[2];
  const float* b0 = (const float*)d_in[3];
  const float* W1 = (const float*)d_in[4];
  const float* b1 = (const float*)d_in[5];
  float* out = (float*)d_out;              // fp32 [n][320]
  const int n = in_sizes[0] / 64;

  bf16* fbuf0 = (bf16*)d_ws;                              // [n][64] bf16 (25.6 MB)
  bf16* fbuf1 = (bf16*)((char*)d_ws + (size_t)n * 64 * 2); // [n][64] bf16 (25.6 MB)

  const int dblocks = (n + 63) / 64;
  const int ablocks = (n + 3) / 4;

  // layer 0: f0 = relu(x@W0+b0) via MFMA; also copy x (fp32) into out cols 256..319
  dense_mfma_kernel<64><<<dblocks, 256, 0, stream>>>(x, 64, W0, b0, fbuf0, out + 256, n);
  // fused: accumulate f0 -> out cols 0..127 AND f1 = relu(out0@W1+b1) (via LDS)
  accum_dense_fused_kernel<<<dblocks, 256, 0, stream>>>(fbuf0, idx, W1, b1, out, fbuf1, n);
  // accumulate f1 -> out cols 128..255
  accum_kernel<<<ablocks, 256, 0, stream>>>(fbuf1, idx, out + 128, n);
}